// Round 7
// baseline (236.440 us; speedup 1.0000x reference)
//
#include <hip/hip_runtime.h>
#include <math.h>

#define BATCH 8
#define CH    256
#define H     128
#define W     128
#define HW    (H * W)          // 16384
#define OH    65
#define OW    65
#define NPIX  (OH * OW)        // 4225

// One block per output row (b, oh), 512 threads = 8 waves.
// Phase 1: channel-L2 norm partial sums via CONTIGUOUS float4 loads — the 3
//   input rows are contiguous per channel (1536 B). Wave w covers channels
//   [32w, 32w+32): per channel one full-wave float4 load (1 KB) + one
//   half-wave float4 load (512 B). Per-position squares accumulate in
//   registers; 8 wave-partials reduce in LDS -> 384 norms.
// Phase A: softmax weights for the row's 65 output pixels (LDS).
// Phase 2: wave pools 32 channels; lane = output pixel; 3 coalesced float2
//   row-loads (cache-hot from phase 1); left taps via shfl_up; OOB taps have
//   exactly-zero weights (verified semantics, absmax 0.0078 since R1).
__global__ __launch_bounds__(512, 4) void fused_kernel(const float* __restrict__ x,
                                                       float* __restrict__ out) {
    __shared__ float part[8][384];   // 12 KB: per-wave sq-sum partials
    __shared__ float nrmabs[3][W];   // 1.5 KB: norms of rows base..base+2
    __shared__ float wts[OW][9];     // 2.3 KB: softmax weights per output pixel
    const int oh   = blockIdx.x;
    const int b    = blockIdx.y;
    const int t    = threadIdx.x;
    const int lane = t & 63;
    const int wv   = t >> 6;

    const int ih0  = 2 * oh - 2;
    int base = ih0 < 0 ? 0 : ih0;            // clamp window base to [0, H-3]
    if (base > H - 3) base = H - 3;

    // ---------- Phase 1: contiguous-load norm partials ----------
    {
        const float* xw = x + (size_t)(b * CH + wv * 32) * HW + base * W;
        float4 a0 = {0.f, 0.f, 0.f, 0.f};
        float4 a1 = {0.f, 0.f, 0.f, 0.f};
        #pragma unroll 4
        for (int c = 0; c < 32; ++c) {
            const float4* p4 = (const float4*)(xw + (size_t)c * HW);
            float4 v0 = p4[lane];                     // floats 4l..4l+3 (rows 0-1)
            a0.x += v0.x * v0.x; a0.y += v0.y * v0.y;
            a0.z += v0.z * v0.z; a0.w += v0.w * v0.w;
            if (lane < 32) {
                float4 v1 = p4[64 + lane];            // floats 256+4l.. (row 2)
                a1.x += v1.x * v1.x; a1.y += v1.y * v1.y;
                a1.z += v1.z * v1.z; a1.w += v1.w * v1.w;
            }
        }
        float4* prow = (float4*)part[wv];
        prow[lane] = a0;                    // part[wv][4l..4l+3]
        if (lane < 32) prow[64 + lane] = a1;
    }
    __syncthreads();

    if (t < 384) {        // reduce 8 wave-partials -> norm of (row t/128, col t%128)
        float s = 0.f;
        #pragma unroll
        for (int w = 0; w < 8; ++w) s += part[w][t];
        nrmabs[t >> 7][t & 127] = sqrtf(s);
    }
    __syncthreads();

    // ---------- Phase A: softmax weights for the 65 output pixels ----------
    if (t < OW) {
        const int iw0 = 2 * t - 2;
        float ww[9];
        bool  vl[9];
        float m = 0.f;                      // OOB norms are 0 -> max starts at 0
        #pragma unroll
        for (int r = 0; r < 3; ++r) {
            int ih = ih0 + r;
            bool vh = (unsigned)ih < (unsigned)H;
            int slot = vh ? (ih - base) : 0;          // in [0,2] when valid
            #pragma unroll
            for (int kw = 0; kw < 3; ++kw) {
                int iw = iw0 + kw;
                bool v = vh && ((unsigned)iw < (unsigned)W);
                int iwc = iw < 0 ? 0 : (iw > W - 1 ? W - 1 : iw);
                float nv = v ? nrmabs[slot][iwc] : 0.f;
                vl[r * 3 + kw] = v;
                ww[r * 3 + kw] = nv;
                m = fmaxf(m, nv);
            }
        }
        float d = 0.f;
        #pragma unroll
        for (int k = 0; k < 9; ++k) {
            float e = __expf(ww[k] - m);    // OOB contributes exp(0-m) to denom
            d += e;
            ww[k] = vl[k] ? e : 0.f;        // but zero weight in numerator
        }
        float inv = 1.f / d;
        #pragma unroll
        for (int k = 0; k < 9; ++k) wts[t][k] = ww[k] * inv;
    }
    __syncthreads();

    // ---------- Phase 2: pooling; wave wv -> channels [32*wv, 32*wv+32) ----------
    float w0[9], w64[9];
    #pragma unroll
    for (int k = 0; k < 9; ++k) { w0[k] = wts[lane][k]; w64[k] = wts[OW - 1][k]; }

    int rb[3];
    #pragma unroll
    for (int r = 0; r < 3; ++r) {
        int ih = ih0 + r;
        int ihc = ih < 0 ? 0 : (ih > H - 1 ? H - 1 : ih);
        rb[r] = ihc * W;                    // clamped; invalid rows have zero weights
    }

    const float* xb = x + (size_t)(b * CH + wv * 32) * HW;
    float*       ob = out + (size_t)(b * CH + wv * 32) * NPIX + oh * OW;

    #pragma unroll 4
    for (int c = 0; c < 32; ++c) {
        const float* xc = xb + (size_t)c * HW;
        float2 own[3], prev[3];
        #pragma unroll
        for (int r = 0; r < 3; ++r)
            own[r] = *(const float2*)(xc + rb[r] + 2 * lane);   // cols 2l, 2l+1
        #pragma unroll
        for (int r = 0; r < 3; ++r) {
            prev[r].x = __shfl_up(own[r].x, 1);                 // col 2l-2
            prev[r].y = __shfl_up(own[r].y, 1);                 // col 2l-1
        }
        float a0 = 0.f, a1 = 0.f;
        #pragma unroll
        for (int r = 0; r < 3; ++r) {
            a0 += w0[r * 3 + 0] * prev[r].x + w0[r * 3 + 1] * prev[r].y
                + w0[r * 3 + 2] * own[r].x;
            a1 += w64[r * 3 + 0] * own[r].x + w64[r * 3 + 1] * own[r].y;
            // pixel 64's third tap (col 128) is OOB -> weight 0
        }
        float* oc = ob + (size_t)c * NPIX;
        oc[lane] = a0;                       // coalesced 256 B store
        if (lane == 63) oc[OW - 1] = a1;     // pixel 64 (taps = lane 63's own)
    }
}

extern "C" void kernel_launch(void* const* d_in, const int* in_sizes, int n_in,
                              void* d_out, int out_size, void* d_ws, size_t ws_size,
                              hipStream_t stream) {
    const float* x = (const float*)d_in[0];
    float* out = (float*)d_out;
    dim3 grid(OH, BATCH);   // 520 blocks x 512 threads
    fused_kernel<<<grid, 512, 0, stream>>>(x, out);
}